// Round 16
// baseline (28.864 us; speedup 1.0000x reference)
//
#include <hip/hip_runtime.h>

constexpr int PL = 128;

typedef float f32x2 __attribute__((ext_vector_type(2)));

__device__ __forceinline__ float fast_exp2(float x) {
#if __has_builtin(__builtin_amdgcn_exp2f)
    return __builtin_amdgcn_exp2f(x);
#else
    return __expf(x * 0.69314718055994531f);   // e^(x ln2) = 2^x
#endif
}
// exact IEEE f32 fma per lane; builtin codegen beat hand asm (r11 A/B)
__device__ __forceinline__ f32x2 pk_fma(f32x2 a, f32x2 b, f32x2 c) {
    return __builtin_elementwise_fma(a, b, c);
}
__device__ __forceinline__ f32x2 sp(float v) { f32x2 r; r.x = v; r.y = v; return r; }

// Phase-2 core over NS compacted row-slots (NS wave-uniform; static arrays only).
template <int NS>
__device__ __forceinline__ void attn_core(
    const float4* __restrict__ CSMc_s, const int* __restrict__ rowList_s,
    const float4* __restrict__ ROWD_s, float* __restrict__ OST_h,
    int npair, int nv, int r0,
    float a0, float be0, float a1, float be1)
{
    const float gam = 0.5f * 1.4426950408889634f;   // 1/sqrt(QK) * log2(e)
    f32x2 A[NS], Bc[NS], Cc[NS], Dc[NS], S[NS], X[NS];
    int  rowv[NS];
    bool act[NS];
    #pragma unroll
    for (int rr = 0; rr < NS; ++rr) {
        const int i = r0 + rr * 32;
        act[rr]  = (i < nv);
        const int row = act[rr] ? rowList_s[i] : 0;
        rowv[rr] = row;
        const float4 rd = ROWD_s[row];
        A[rr]  = sp(gam * (rd.x * a0 + rd.y * be0));
        Bc[rr] = sp(gam * (rd.y * a0 - rd.x * be0));
        Cc[rr] = sp(gam * (rd.z * a1 + rd.w * be1));
        Dc[rr] = sp(gam * (rd.w * a1 - rd.z * be1));
        S[rr]  = sp(0.f);
        X[rr]  = sp(0.f);
    }
    #pragma unroll 2
    for (int jj = 0; jj < npair; ++jj) {
        const float4 ca = CSMc_s[jj * 3 + 0];   // wave-uniform broadcast b128
        const float4 cb = CSMc_s[jj * 3 + 1];
        const float4 mm = CSMc_s[jj * 3 + 2];
        f32x2 c0p; c0p.x = ca.x; c0p.y = ca.y;
        f32x2 s0p; s0p.x = ca.z; s0p.y = ca.w;
        f32x2 c1p; c1p.x = cb.x; c1p.y = cb.y;
        f32x2 s1p; s1p.x = cb.z; s1p.y = cb.w;
        f32x2 vv;  vv.x  = mm.x; vv.y  = mm.y;
        f32x2 vx;  vx.x  = mm.z; vx.y  = mm.w;
        #pragma unroll
        for (int rr = 0; rr < NS; ++rr) {
            f32x2 L = A[rr] * c0p;
            L = pk_fma(Bc[rr], s0p, L);
            L = pk_fma(Cc[rr], c1p, L);
            L = pk_fma(Dc[rr], s1p, L);
            f32x2 E;
            E.x = fast_exp2(L.x);
            E.y = fast_exp2(L.y);
            S[rr] = pk_fma(E, vv, S[rr]);
            X[rr] = pk_fma(E, vx, X[rr]);
        }
    }
    #pragma unroll
    for (int rr = 0; rr < NS; ++rr) {
        if (act[rr]) {
            const float s  = S[rr].x + S[rr].y;
            const float wx = X[rr].x + X[rr].y;
            OST_h[rowv[rr]] = wx / s;           // compacted rows are all valid
        }
    }
}

__global__ __launch_bounds__(256, 4) void fused_block_kernel(
    const float* __restrict__ x, const float* __restrict__ t, const int* __restrict__ mask,
    const float* __restrict__ Wq, const float* __restrict__ Wk, const float* __restrict__ Wv,
    const float* __restrict__ Wout, const float* __restrict__ W1, const float* __restrict__ b1,
    const float* __restrict__ W2, const float* __restrict__ b2,
    float* __restrict__ out)
{
    // Two sequences per block. Keys AND query rows compacted to valid positions.
    __shared__ float4 CSMc[2][64 * 3];
    __shared__ float4 ROWD[2][PL];      // per-row {x*c0, x*s0, x*c1, x*s1}
    __shared__ float  validR[2][PL];
    __shared__ int    rowList[2][PL];   // compacted valid positions
    __shared__ f32x2  w1p[32][16];      // [hid-pair][dim]
    __shared__ __align__(8) float cg[64];
    __shared__ __align__(8) float b1s[64];
    __shared__ float  OST[2][4][PL];
    __shared__ float  xpart[2][2];
    __shared__ int    wcnt[2][2];       // valid count per (seq, wave-half)
    __shared__ __align__(16) float woutS[16];
    __shared__ float  bbS;

    const int tid  = threadIdx.x;
    const int blk  = blockIdx.x;        // sequences 2*blk, 2*blk+1
    const int seq  = tid >> 7;
    const int j    = tid & 127;
    const int lane = tid & 63;
    const int wh   = (tid >> 6) & 1;    // wave-half within seq (j<64 / j>=64)

    // ---- Phase 1: per-position trig + row data + valid ballot ----
    const float xv = x[(blk * 2 + seq) * PL + j];
    const float tv = t[(blk * 2 + seq) * PL + j];
    const int   mv = mask[(blk * 2 + seq) * PL + j];
    const float va = mv ? 1.0f : 0.0f;
    float xc0v, xs0v, xc1v, xs1v;
    {
        const float th1 = 0.031622776601683794f;   // 1000^-0.5
        xc0v = xv * __cosf(tv);        xs0v = xv * __sinf(tv);
        xc1v = xv * __cosf(tv * th1);  xs1v = xv * __sinf(tv * th1);
        ROWD[seq][j]   = make_float4(xc0v, xs0v, xc1v, xs1v);
        validR[seq][j] = va;
        float px = xv;
        #pragma unroll
        for (int off = 32; off >= 1; off >>= 1) px += __shfl_xor(px, off);
        if (lane == 0) xpart[seq][wh] = px;
    }
    const unsigned long long ball = __ballot(mv != 0);
    const int lpos = __popcll(ball & ((1ull << lane) - 1ull));
    if (lane == 0) wcnt[seq][wh] = __popcll(ball);

    // ---- weight staging ----
    #pragma unroll
    for (int k = 0; k < 4; ++k) {
        const int idx = tid + k * 256;
        const int hid = idx >> 4, d = idx & 15;
        reinterpret_cast<float*>(w1p)[((hid >> 1) * 16 + d) * 2 + (hid & 1)] = W1[idx];
    }
    if (tid < 64) {
        b1s[tid] = b1[tid];
        float c = 0.f;
        #pragma unroll
        for (int d = 0; d < 16; ++d) c += W2[d * 64 + tid] * Wout[d];   // W2^T @ wout
        cg[tid] = c;
    }
    if (tid < 16) woutS[tid] = Wout[tid];
    if (tid == 0) {
        float bb = 0.f;
        #pragma unroll
        for (int d = 0; d < 16; ++d) bb += b2[d] * Wout[d];
        bbS = bb;
    }
    __syncthreads();

    // ---- Phase 1b: scatter valid j-records into compacted slots + row list ----
    {
        float* C = reinterpret_cast<float*>(CSMc[seq]);
        const int pos = lpos + (wh ? wcnt[seq][0] : 0);
        if (mv) {
            const int p = pos >> 1, par = pos & 1;
            C[p*12 + 0 + par] = xc0v;
            C[p*12 + 2 + par] = xs0v;
            C[p*12 + 4 + par] = xc1v;
            C[p*12 + 6 + par] = xs1v;
            C[p*12 + 8 + par] = 1.0f;
            C[p*12 +10 + par] = xv;
            rowList[seq][pos] = j;
        }
        const int nv = wcnt[seq][0] + wcnt[seq][1];
        if (j == 0 && (nv & 1)) {       // zero the odd-tail pad slot (vv=0 -> contributes 0)
            const int p = nv >> 1;
            C[p*12 + 1] = 0.f; C[p*12 + 3] = 0.f; C[p*12 + 5] = 0.f;
            C[p*12 + 7] = 0.f; C[p*12 + 9] = 0.f; C[p*12 +11] = 0.f;
        }
    }
    __syncthreads();

    // ---- Phase 2: attention over compacted keys AND compacted rows ----
    {
        const int wave = tid >> 6;
        const int sq   = wave >> 1;
        const int hh   = wave & 1;
        const int l2   = tid & 63;
        const int h    = hh * 2 + (l2 >> 5);     // 2 heads per wave
        const int r0   = l2 & 31;                // compacted row idx = r0 + 32*rr
        const float4 wq4 = reinterpret_cast<const float4*>(Wq)[h];
        const float4 wk4 = reinterpret_cast<const float4*>(Wk)[h];
        const float a0  = wq4.x*wk4.x + wq4.y*wk4.y;
        const float be0 = wq4.x*wk4.y - wq4.y*wk4.x;
        const float a1  = wq4.z*wk4.z + wq4.w*wk4.w;
        const float be1 = wq4.z*wk4.w - wq4.w*wk4.z;

        const int nv    = wcnt[sq][0] + wcnt[sq][1];
        const int npair = (nv + 1) >> 1;
        const int nslot = (nv + 31) >> 5;        // wave-uniform
        const float4* Cs = CSMc[sq];
        const int*    rl = rowList[sq];
        const float4* rd = ROWD[sq];
        float*        oh = &OST[sq][h][0];
        switch (nslot) {                          // wave-uniform dispatch, static slots
            case 0: break;
            case 1: attn_core<1>(Cs, rl, rd, oh, npair, nv, r0, a0, be0, a1, be1); break;
            case 2: attn_core<2>(Cs, rl, rd, oh, npair, nv, r0, a0, be0, a1, be1); break;
            case 3: attn_core<3>(Cs, rl, rd, oh, npair, nv, r0, a0, be0, a1, be1); break;
            default: attn_core<4>(Cs, rl, rd, oh, npair, nv, r0, a0, be0, a1, be1); break;
        }
    }
    __syncthreads();

    // ---- Phase 3: o = wv (x) o_scal; out = o.wout + bb + sum cg*relu(o.W1+b1) ----
    {
        const int qi = j;
        const bool mq = validR[seq][qi] != 0.f;
        const float sm = (xpart[seq][0] + xpart[seq][1]) * (1.0f / 128.0f);
        // masked query row: uniform softmax over ALL j -> o_scal = sum(x)/128
        const float os0 = mq ? OST[seq][0][qi] : sm;
        const float os1 = mq ? OST[seq][1][qi] : sm;
        const float os2 = mq ? OST[seq][2][qi] : sm;
        const float os3 = mq ? OST[seq][3][qi] : sm;
        const float4 wv0 = reinterpret_cast<const float4*>(Wv)[0];
        const float4 wv1 = reinterpret_cast<const float4*>(Wv)[1];
        const float4 wv2 = reinterpret_cast<const float4*>(Wv)[2];
        const float4 wv3 = reinterpret_cast<const float4*>(Wv)[3];
        float o[16];
        o[ 0] = wv0.x*os0; o[ 1] = wv0.y*os0; o[ 2] = wv0.z*os0; o[ 3] = wv0.w*os0;
        o[ 4] = wv1.x*os1; o[ 5] = wv1.y*os1; o[ 6] = wv1.z*os1; o[ 7] = wv1.w*os1;
        o[ 8] = wv2.x*os2; o[ 9] = wv2.y*os2; o[10] = wv2.z*os2; o[11] = wv2.w*os2;
        o[12] = wv3.x*os3; o[13] = wv3.y*os3; o[14] = wv3.z*os3; o[15] = wv3.w*os3;

        const f32x2* b1pair = reinterpret_cast<const f32x2*>(b1s);
        const f32x2* cgpair = reinterpret_cast<const f32x2*>(cg);
        f32x2 R2 = sp(0.f);
        #pragma unroll 4
        for (int p = 0; p < 32; ++p) {
            f32x2 HS = b1pair[p];
            #pragma unroll
            for (int d = 0; d < 16; ++d) HS = pk_fma(w1p[p][d], sp(o[d]), HS);
            HS.x = fmaxf(HS.x, 0.f);
            HS.y = fmaxf(HS.y, 0.f);
            R2 = pk_fma(cgpair[p], HS, R2);
        }
        float r = R2.x + R2.y + bbS;
        #pragma unroll
        for (int d = 0; d < 16; ++d) r += o[d] * woutS[d];
        out[(blk * 2 + seq) * PL + qi] = r;
    }
}

extern "C" void kernel_launch(void* const* d_in, const int* in_sizes, int n_in,
                              void* d_out, int out_size, void* d_ws, size_t ws_size,
                              hipStream_t stream) {
    const float* x    = (const float*)d_in[0];
    const float* t    = (const float*)d_in[1];
    const int*   mask = (const int*)d_in[2];
    const float* Wq   = (const float*)d_in[3];
    const float* Wk   = (const float*)d_in[4];
    const float* Wv   = (const float*)d_in[5];
    const float* Wout = (const float*)d_in[6];
    const float* W1   = (const float*)d_in[7];
    const float* b1   = (const float*)d_in[8];
    const float* W2   = (const float*)d_in[9];
    const float* b2   = (const float*)d_in[10];
    float* outp = (float*)d_out;
    const int B  = in_sizes[0] / PL;    // 2048 sequences
    const int B2 = B / 2;               // 2 sequences per block
    fused_block_kernel<<<B2, 256, 0, stream>>>(x, t, mask, Wq, Wk, Wv, Wout, W1, b1, W2, b2, outp);
}

// Round 17
// 23.864 us; speedup vs baseline: 1.2095x; 1.2095x over previous
//
#include <hip/hip_runtime.h>

constexpr int PL = 128;

typedef float f32x2 __attribute__((ext_vector_type(2)));

__device__ __forceinline__ float fast_exp2(float x) {
#if __has_builtin(__builtin_amdgcn_exp2f)
    return __builtin_amdgcn_exp2f(x);
#else
    return __expf(x * 0.69314718055994531f);   // e^(x ln2) = 2^x
#endif
}
// exact IEEE f32 fma per lane; builtin codegen beat hand asm (r11 A/B)
__device__ __forceinline__ f32x2 pk_fma(f32x2 a, f32x2 b, f32x2 c) {
    return __builtin_elementwise_fma(a, b, c);
}
__device__ __forceinline__ f32x2 sp(float v) { f32x2 r; r.x = v; r.y = v; return r; }

__global__ __launch_bounds__(256, 4) void fused_block_kernel(
    const float* __restrict__ x, const float* __restrict__ t, const int* __restrict__ mask,
    const float* __restrict__ Wq, const float* __restrict__ Wk, const float* __restrict__ Wv,
    const float* __restrict__ Wout, const float* __restrict__ W1, const float* __restrict__ b1,
    const float* __restrict__ W2, const float* __restrict__ b2,
    float* __restrict__ out)
{
    // Two sequences per block. Keys compacted to valid positions (round-15 winner).
    // CSMc[s][p*3+0] = {x*c0(a), x*c0(b), x*s0(a), x*s0(b)}   (a,b = compacted pair)
    // CSMc[s][p*3+1] = {x*c1, x*c1', x*s1, x*s1'}
    // CSMc[s][p*3+2] = {1, 1, x, x'}          (pad slot zeroed -> contributes 0)
    __shared__ float4 CSMc[2][64 * 3];
    __shared__ float4 ROWD[2][PL];      // per-row {x*c0, x*s0, x*c1, x*s1}
    __shared__ float  validR[2][PL];
    __shared__ f32x2  Gp[32][4];        // G pairs: Gp[p][h] = {G[2p][h], G[2p+1][h]}
    __shared__ __align__(8) float cg[64];
    __shared__ __align__(8) float b1s[64];
    __shared__ float  OST[2][4][PL];
    __shared__ float  xpart[2][2];
    __shared__ int    wcnt[2][2];       // valid count per (seq, wave-half)
    __shared__ float  gwS[4];           // gw[h] = wv_h . wout_h
    __shared__ float  bbS;

    const int tid  = threadIdx.x;
    const int blk  = blockIdx.x;        // sequences 2*blk, 2*blk+1
    const int seq  = tid >> 7;
    const int j    = tid & 127;
    const int lane = tid & 63;
    const int wh   = (tid >> 6) & 1;    // wave-half within seq (j<64 / j>=64)

    // ---- Phase 1: per-position trig + row data + valid ballot ----
    const float xv = x[(blk * 2 + seq) * PL + j];
    const float tv = t[(blk * 2 + seq) * PL + j];
    const int   mv = mask[(blk * 2 + seq) * PL + j];
    const float va = mv ? 1.0f : 0.0f;
    float xc0v, xs0v, xc1v, xs1v;
    {
        const float th1 = 0.031622776601683794f;   // 1000^-0.5
        xc0v = xv * __cosf(tv);        xs0v = xv * __sinf(tv);
        xc1v = xv * __cosf(tv * th1);  xs1v = xv * __sinf(tv * th1);
        ROWD[seq][j]   = make_float4(xc0v, xs0v, xc1v, xs1v);
        validR[seq][j] = va;
        float px = xv;
        #pragma unroll
        for (int off = 32; off >= 1; off >>= 1) px += __shfl_xor(px, off);
        if (lane == 0) xpart[seq][wh] = px;
    }
    const unsigned long long ball = __ballot(mv != 0);
    const int lpos = __popcll(ball & ((1ull << lane) - 1ull));
    if (lane == 0) wcnt[seq][wh] = __popcll(ball);

    // ---- weight staging: fold FFN through the rank-4 latent (G = W1 @ diag-blocks(Wv)) ----
    if (tid < 64) {
        const int hid = tid;
        b1s[hid] = b1[hid];
        float c = 0.f;
        #pragma unroll
        for (int d = 0; d < 16; ++d) c += W2[d * 64 + hid] * Wout[d];   // W2^T @ wout
        cg[hid] = c;
        const float4* w1r = reinterpret_cast<const float4*>(W1 + hid * 16);
        #pragma unroll
        for (int h = 0; h < 4; ++h) {
            const float4 wv  = reinterpret_cast<const float4*>(Wv)[h];
            const float4 w1v = w1r[h];
            const float g = w1v.x*wv.x + w1v.y*wv.y + w1v.z*wv.z + w1v.w*wv.w;
            reinterpret_cast<float*>(&Gp[hid >> 1][h])[hid & 1] = g;
        }
    } else if (tid < 68) {
        const int h = tid - 64;
        const float4 wv = reinterpret_cast<const float4*>(Wv)[h];
        const float4 wo = reinterpret_cast<const float4*>(Wout)[h];
        gwS[h] = wv.x*wo.x + wv.y*wo.y + wv.z*wo.z + wv.w*wo.w;
    } else if (tid == 68) {
        float bb = 0.f;
        #pragma unroll
        for (int d = 0; d < 16; ++d) bb += b2[d] * Wout[d];
        bbS = bb;
    }
    __syncthreads();

    // ---- Phase 1b: scatter valid j-records into compacted slots ----
    {
        float* C = reinterpret_cast<float*>(CSMc[seq]);
        const int pos = lpos + (wh ? wcnt[seq][0] : 0);
        if (mv) {
            const int p = pos >> 1, par = pos & 1;
            C[p*12 + 0 + par] = xc0v;
            C[p*12 + 2 + par] = xs0v;
            C[p*12 + 4 + par] = xc1v;
            C[p*12 + 6 + par] = xs1v;
            C[p*12 + 8 + par] = 1.0f;
            C[p*12 +10 + par] = xv;
        }
        const int nv = wcnt[seq][0] + wcnt[seq][1];
        if (j == 0 && (nv & 1)) {       // zero the odd-tail pad slot (vv=0 -> contributes 0)
            const int p = nv >> 1;
            C[p*12 + 1] = 0.f; C[p*12 + 3] = 0.f; C[p*12 + 5] = 0.f;
            C[p*12 + 7] = 0.f; C[p*12 + 9] = 0.f; C[p*12 +11] = 0.f;
        }
    }
    __syncthreads();

    // ---- Phase 2: attention over compacted (valid-only) keys; 4 rows/lane (r15) ----
    {
        const int wave = tid >> 6;
        const int sq   = wave >> 1;
        const int hh   = wave & 1;
        const int l2   = tid & 63;
        const int h    = hh * 2 + (l2 >> 5);     // 2 heads per wave
        const int r0   = l2 & 31;                // rows r0 + 32*rr
        const float4 wq4 = reinterpret_cast<const float4*>(Wq)[h];
        const float4 wk4 = reinterpret_cast<const float4*>(Wk)[h];
        const float a0  = wq4.x*wk4.x + wq4.y*wk4.y;
        const float be0 = wq4.x*wk4.y - wq4.y*wk4.x;
        const float a1  = wq4.z*wk4.z + wq4.w*wk4.w;
        const float be1 = wq4.z*wk4.w - wq4.w*wk4.z;
        const float gam = 0.5f * 1.4426950408889634f;   // 1/sqrt(QK) * log2(e)

        f32x2 A[4], Bc[4], Cc[4], Dc[4], S[4], X[4];
        #pragma unroll
        for (int rr = 0; rr < 4; ++rr) {
            const int r = r0 + rr * 32;
            const float4 rd = ROWD[sq][r];
            A[rr]  = sp(gam * (rd.x * a0 + rd.y * be0));
            Bc[rr] = sp(gam * (rd.y * a0 - rd.x * be0));
            Cc[rr] = sp(gam * (rd.z * a1 + rd.w * be1));
            Dc[rr] = sp(gam * (rd.w * a1 - rd.z * be1));
            S[rr] = sp(0.f);
            X[rr] = sp(0.f);
        }
        const int nv    = wcnt[sq][0] + wcnt[sq][1];
        const int npair = (nv + 1) >> 1;
        #pragma unroll 2
        for (int jj = 0; jj < npair; ++jj) {
            const float4 ca = CSMc[sq][jj * 3 + 0];   // wave-uniform broadcast b128
            const float4 cb = CSMc[sq][jj * 3 + 1];
            const float4 mm = CSMc[sq][jj * 3 + 2];
            f32x2 c0p; c0p.x = ca.x; c0p.y = ca.y;
            f32x2 s0p; s0p.x = ca.z; s0p.y = ca.w;
            f32x2 c1p; c1p.x = cb.x; c1p.y = cb.y;
            f32x2 s1p; s1p.x = cb.z; s1p.y = cb.w;
            f32x2 vv;  vv.x  = mm.x; vv.y  = mm.y;
            f32x2 vx;  vx.x  = mm.z; vx.y  = mm.w;
            #pragma unroll
            for (int rr = 0; rr < 4; ++rr) {
                f32x2 L = A[rr] * c0p;
                L = pk_fma(Bc[rr], s0p, L);
                L = pk_fma(Cc[rr], c1p, L);
                L = pk_fma(Dc[rr], s1p, L);
                f32x2 E;
                E.x = fast_exp2(L.x);
                E.y = fast_exp2(L.y);
                S[rr] = pk_fma(E, vv, S[rr]);
                X[rr] = pk_fma(E, vx, X[rr]);
            }
        }
        const float sumx = xpart[sq][0] + xpart[sq][1];
        #pragma unroll
        for (int rr = 0; rr < 4; ++rr) {
            const int r = r0 + rr * 32;
            const float s  = S[rr].x + S[rr].y;
            const float wx = X[rr].x + X[rr].y;
            const bool  m  = validR[sq][r] != 0.f;
            // masked query row: uniform softmax over ALL j -> o_scal = sumx/128
            OST[sq][h][r] = (m ? wx : sumx) / (m ? s : 128.f);
        }
    }
    __syncthreads();

    // ---- Phase 3 (G-folded): hsum = b1 + G @ os; out = os.gw + bb + cg.relu(hsum) ----
    {
        const int qi = j;
        const float os0 = OST[seq][0][qi];
        const float os1 = OST[seq][1][qi];
        const float os2 = OST[seq][2][qi];
        const float os3 = OST[seq][3][qi];
        const f32x2* b1pair = reinterpret_cast<const f32x2*>(b1s);
        const f32x2* cgpair = reinterpret_cast<const f32x2*>(cg);
        const f32x2 q0 = sp(os0), q1 = sp(os1), q2 = sp(os2), q3 = sp(os3);
        f32x2 R2 = sp(0.f);
        #pragma unroll 8
        for (int p = 0; p < 32; ++p) {
            f32x2 HS = b1pair[p];
            HS = pk_fma(Gp[p][0], q0, HS);
            HS = pk_fma(Gp[p][1], q1, HS);
            HS = pk_fma(Gp[p][2], q2, HS);
            HS = pk_fma(Gp[p][3], q3, HS);
            HS.x = fmaxf(HS.x, 0.f);
            HS.y = fmaxf(HS.y, 0.f);
            R2 = pk_fma(cgpair[p], HS, R2);
        }
        const float r = R2.x + R2.y + bbS
                      + os0 * gwS[0] + os1 * gwS[1] + os2 * gwS[2] + os3 * gwS[3];
        out[(blk * 2 + seq) * PL + qi] = r;
    }
}

extern "C" void kernel_launch(void* const* d_in, const int* in_sizes, int n_in,
                              void* d_out, int out_size, void* d_ws, size_t ws_size,
                              hipStream_t stream) {
    const float* x    = (const float*)d_in[0];
    const float* t    = (const float*)d_in[1];
    const int*   mask = (const int*)d_in[2];
    const float* Wq   = (const float*)d_in[3];
    const float* Wk   = (const float*)d_in[4];
    const float* Wv   = (const float*)d_in[5];
    const float* Wout = (const float*)d_in[6];
    const float* W1   = (const float*)d_in[7];
    const float* b1   = (const float*)d_in[8];
    const float* W2   = (const float*)d_in[9];
    const float* b2   = (const float*)d_in[10];
    float* outp = (float*)d_out;
    const int B  = in_sizes[0] / PL;    // 2048 sequences
    const int B2 = B / 2;               // 2 sequences per block
    fused_block_kernel<<<B2, 256, 0, stream>>>(x, t, mask, Wq, Wk, Wv, Wout, W1, b1, W2, b2, outp);
}